// Round 1
// baseline (106.068 us; speedup 1.0000x reference)
//
#include <hip/hip_runtime.h>

#define T_STEPS 512

#if __has_builtin(__builtin_amdgcn_exp2f)
__device__ __forceinline__ float exp2_fast(float x) { return __builtin_amdgcn_exp2f(x); }
#else
__device__ __forceinline__ float exp2_fast(float x) { return exp2f(x); }
#endif

#if __has_builtin(__builtin_amdgcn_rcpf)
__device__ __forceinline__ float rcp_fast(float x) { return __builtin_amdgcn_rcpf(x); }
#else
__device__ __forceinline__ float rcp_fast(float x) { return 1.0f / x; }
#endif

// sigmoid(x) = 1 / (1 + exp2(-x*log2(e)))
__device__ __forceinline__ float sig_fast(float x) {
    return rcp_fast(1.0f + exp2_fast(x * -1.4426950408889634f));
}
// tanh(x) = 2*sigmoid(2x) - 1
__device__ __forceinline__ float tanh_fast(float x) {
    float s = rcp_fast(1.0f + exp2_fast(x * -2.8853900817779268f));
    return fmaf(2.0f, s, -1.0f);
}

// One thread per batch element: run the full 512-step LSTM recurrence with
// H=2 state entirely in registers, then the fused relu->fc1(128)->relu->fc(1)
// head. Weight reads are wave-uniform -> scalar loads.
__global__ __launch_bounds__(64) void lstm_fused(
    const float* __restrict__ x,      // [B, T, 1]
    const float* __restrict__ W_ih,   // [8, 1]
    const float* __restrict__ W_hh,   // [8, 2]
    const float* __restrict__ b_ih,   // [8]
    const float* __restrict__ b_hh,   // [8]
    const float* __restrict__ fc1_w,  // [128, 2]
    const float* __restrict__ fc1_b,  // [128]
    const float* __restrict__ fc_w,   // [1, 128]
    const float* __restrict__ fc_b,   // [1]
    float* __restrict__ out,          // [B, 1]
    int B)
{
    int b = blockIdx.x * 64 + threadIdx.x;
    if (b >= B) return;

    // Gate order (PyTorch): rows 0-1 = i, 2-3 = f, 4-5 = g, 6-7 = o
    float a[8], bs[8], u0[8], u1[8];
#pragma unroll
    for (int g = 0; g < 8; ++g) {
        a[g]  = W_ih[g];
        bs[g] = b_ih[g] + b_hh[g];
        u0[g] = W_hh[2 * g];
        u1[g] = W_hh[2 * g + 1];
    }

    float h0 = 0.f, h1 = 0.f, c0 = 0.f, c1 = 0.f;
    const float4* xv = reinterpret_cast<const float4*>(x + (size_t)b * T_STEPS);

#pragma unroll 1
    for (int t4 = 0; t4 < T_STEPS / 4; ++t4) {
        float4 xq = xv[t4];
        float xs4[4] = {xq.x, xq.y, xq.z, xq.w};
#pragma unroll
        for (int k = 0; k < 4; ++k) {
            float xs = xs4[k];
            float gi0 = fmaf(h1, u1[0], fmaf(h0, u0[0], fmaf(xs, a[0], bs[0])));
            float gi1 = fmaf(h1, u1[1], fmaf(h0, u0[1], fmaf(xs, a[1], bs[1])));
            float gf0 = fmaf(h1, u1[2], fmaf(h0, u0[2], fmaf(xs, a[2], bs[2])));
            float gf1 = fmaf(h1, u1[3], fmaf(h0, u0[3], fmaf(xs, a[3], bs[3])));
            float gg0 = fmaf(h1, u1[4], fmaf(h0, u0[4], fmaf(xs, a[4], bs[4])));
            float gg1 = fmaf(h1, u1[5], fmaf(h0, u0[5], fmaf(xs, a[5], bs[5])));
            float go0 = fmaf(h1, u1[6], fmaf(h0, u0[6], fmaf(xs, a[6], bs[6])));
            float go1 = fmaf(h1, u1[7], fmaf(h0, u0[7], fmaf(xs, a[7], bs[7])));

            float i0 = sig_fast(gi0), i1 = sig_fast(gi1);
            float f0 = sig_fast(gf0), f1 = sig_fast(gf1);
            float g0 = tanh_fast(gg0), g1 = tanh_fast(gg1);
            float o0 = sig_fast(go0), o1 = sig_fast(go1);

            c0 = fmaf(f0, c0, i0 * g0);
            c1 = fmaf(f1, c1, i1 * g1);
            h0 = o0 * tanh_fast(c0);
            h1 = o1 * tanh_fast(c1);
        }
    }

    // Head: relu -> fc1 (2->128) -> relu -> fc (128->1)
    float hr0 = fmaxf(h0, 0.f), hr1 = fmaxf(h1, 0.f);
    float acc = fc_b[0];
#pragma unroll 8
    for (int j = 0; j < 128; ++j) {
        float v = fmaf(hr1, fc1_w[2 * j + 1], fmaf(hr0, fc1_w[2 * j], fc1_b[j]));
        acc = fmaf(fmaxf(v, 0.f), fc_w[j], acc);
    }
    out[b] = acc;
}

extern "C" void kernel_launch(void* const* d_in, const int* in_sizes, int n_in,
                              void* d_out, int out_size, void* d_ws, size_t ws_size,
                              hipStream_t stream) {
    const float* x     = (const float*)d_in[0];
    const float* W_ih  = (const float*)d_in[1];
    const float* W_hh  = (const float*)d_in[2];
    const float* b_ih  = (const float*)d_in[3];
    const float* b_hh  = (const float*)d_in[4];
    const float* fc1_w = (const float*)d_in[5];
    const float* fc1_b = (const float*)d_in[6];
    const float* fc_w  = (const float*)d_in[7];
    const float* fc_b  = (const float*)d_in[8];

    int B = in_sizes[0] / T_STEPS;  // 32768
    int grid = (B + 63) / 64;       // 512 blocks x 64 threads -> 2 blocks/CU
    lstm_fused<<<grid, 64, 0, stream>>>(x, W_ih, W_hh, b_ih, b_hh,
                                        fc1_w, fc1_b, fc_w, fc_b,
                                        (float*)d_out, B);
}

// Round 2
// 62.869 us; speedup vs baseline: 1.6871x; 1.6871x over previous
//
#include <hip/hip_runtime.h>

#define T_STEPS 512

__device__ __forceinline__ float exp2_fast(float x) {
#if __has_builtin(__builtin_amdgcn_exp2f)
    return __builtin_amdgcn_exp2f(x);
#else
    return exp2f(x);
#endif
}
__device__ __forceinline__ float rcp_fast(float x) {
#if __has_builtin(__builtin_amdgcn_rcpf)
    return __builtin_amdgcn_rcpf(x);
#else
    return 1.0f / x;
#endif
}

// Swap adjacent lanes (lane ^ 1) via DPP quad_perm [1,0,3,2] = 0xB1.
// Full-rate VALU op; far cheaper than ds_swizzle/bpermute.
__device__ __forceinline__ float swap_pair(float v) {
    int r = __builtin_amdgcn_update_dpp(0, __float_as_int(v), 0xB1, 0xF, 0xF, true);
    return __int_as_float(r);
}

// Two lanes per batch element: lane (2k) owns hidden unit 0, lane (2k+1) owns
// hidden unit 1. Each lane computes its unit's 4 gates + cell update; the
// partner's h arrives via one DPP swap per step. The exp2 scale constants
// (-log2e for sigmoid rows, -2*log2e for the tanh row) are pre-folded into
// the gate weights/biases so each gate activation is rcp(1+exp2(z)) directly.
__global__ __launch_bounds__(64) void lstm_fused2(
    const float* __restrict__ x,      // [B, T]
    const float* __restrict__ W_ih,   // [8]
    const float* __restrict__ W_hh,   // [8, 2]
    const float* __restrict__ b_ih,   // [8]
    const float* __restrict__ b_hh,   // [8]
    const float* __restrict__ fc1_w,  // [128, 2]
    const float* __restrict__ fc1_b,  // [128]
    const float* __restrict__ fc_w,   // [128]
    const float* __restrict__ fc_b,   // [1]
    float* __restrict__ out,          // [B]
    int B)
{
    const int lane = threadIdx.x;
    const int j    = lane & 1;                    // hidden unit this lane owns
    const int e    = blockIdx.x * 32 + (lane >> 1);  // batch element
    if (e >= B) return;

    const float SIG = -1.4426950408889634f;       // -log2(e)
    const float TNH = -2.8853900817779268f;       // -2*log2(e)

    // Gate rows (PyTorch order): i=0+j, f=2+j, g=4+j, o=6+j.
    float a_[4], b_[4], us_[4], uo_[4];
#pragma unroll
    for (int t = 0; t < 4; ++t) {
        int r   = 2 * t + j;
        float s = (t == 2) ? TNH : SIG;
        a_[t]  = W_ih[r] * s;
        b_[t]  = (b_ih[r] + b_hh[r]) * s;
        us_[t] = W_hh[2 * r + j] * s;             // own-unit h coefficient
        uo_[t] = W_hh[2 * r + (j ^ 1)] * s;       // partner-unit h coefficient
    }

    float h = 0.f, c = 0.f;
    const float4* xv = reinterpret_cast<const float4*>(x + (size_t)e * T_STEPS);

#pragma unroll 1
    for (int t4 = 0; t4 < T_STEPS / 4; ++t4) {
        float4 xq = xv[t4];
        float xs4[4] = {xq.x, xq.y, xq.z, xq.w};
#pragma unroll
        for (int k = 0; k < 4; ++k) {
            float xs = xs4[k];
            float ho = swap_pair(h);
            float zi = fmaf(ho, uo_[0], fmaf(h, us_[0], fmaf(xs, a_[0], b_[0])));
            float zf = fmaf(ho, uo_[1], fmaf(h, us_[1], fmaf(xs, a_[1], b_[1])));
            float zg = fmaf(ho, uo_[2], fmaf(h, us_[2], fmaf(xs, a_[2], b_[2])));
            float zo = fmaf(ho, uo_[3], fmaf(h, us_[3], fmaf(xs, a_[3], b_[3])));
            // sigmoid(p) = rcp(1 + exp2(SIG*p)); tanh(p) = 2*rcp(1+exp2(TNH*p)) - 1
            float ii = rcp_fast(1.f + exp2_fast(zi));
            float ff = rcp_fast(1.f + exp2_fast(zf));
            float tg = rcp_fast(1.f + exp2_fast(zg));
            float oo = rcp_fast(1.f + exp2_fast(zo));
            float gg = fmaf(2.f, tg, -1.f);
            c = fmaf(ff, c, ii * gg);
            float tc = rcp_fast(1.f + exp2_fast(c * TNH));
            h = oo * fmaf(2.f, tc, -1.f);
        }
    }

    // Head: relu -> fc1 (2->128) -> relu -> fc (128->1), split across the
    // lane pair (each lane does 64 of the 128 hidden terms).
    float hr  = fmaxf(h, 0.f);
    float hro = swap_pair(hr);
    float h0 = j ? hro : hr;
    float h1 = j ? hr : hro;

    float part = 0.f;
    const float2* w2 = reinterpret_cast<const float2*>(fc1_w);
    int base = j * 64;
#pragma unroll 4
    for (int m = 0; m < 64; ++m) {
        int jj = base + m;
        float2 w = w2[jj];
        float v = fmaf(h1, w.y, fmaf(h0, w.x, fc1_b[jj]));
        part = fmaf(fmaxf(v, 0.f), fc_w[jj], part);
    }
    part += swap_pair(part);
    if (j == 0) out[e] = part + fc_b[0];
}

extern "C" void kernel_launch(void* const* d_in, const int* in_sizes, int n_in,
                              void* d_out, int out_size, void* d_ws, size_t ws_size,
                              hipStream_t stream) {
    const float* x     = (const float*)d_in[0];
    const float* W_ih  = (const float*)d_in[1];
    const float* W_hh  = (const float*)d_in[2];
    const float* b_ih  = (const float*)d_in[3];
    const float* b_hh  = (const float*)d_in[4];
    const float* fc1_w = (const float*)d_in[5];
    const float* fc1_b = (const float*)d_in[6];
    const float* fc_w  = (const float*)d_in[7];
    const float* fc_b  = (const float*)d_in[8];

    int B = in_sizes[0] / T_STEPS;        // 32768
    int grid = (B + 31) / 32;             // 1024 blocks x 64 thr = 1024 waves = 1/SIMD
    lstm_fused2<<<grid, 64, 0, stream>>>(x, W_ih, W_hh, b_ih, b_hh,
                                         fc1_w, fc1_b, fc_w, fc_b,
                                         (float*)d_out, B);
}

// Round 3
// 57.644 us; speedup vs baseline: 1.8400x; 1.0906x over previous
//
#include <hip/hip_runtime.h>

#define T_STEPS 512

__device__ __forceinline__ float exp2_fast(float x) {
#if __has_builtin(__builtin_amdgcn_exp2f)
    return __builtin_amdgcn_exp2f(x);
#else
    return exp2f(x);
#endif
}
__device__ __forceinline__ float rcp_fast(float x) {
#if __has_builtin(__builtin_amdgcn_rcpf)
    return __builtin_amdgcn_rcpf(x);
#else
    return 1.0f / x;
#endif
}

// Swap adjacent lanes (lane ^ 1) via DPP quad_perm [1,0,3,2] = 0xB1.
__device__ __forceinline__ float swap_pair(float v) {
    int r = __builtin_amdgcn_update_dpp(0, __float_as_int(v), 0xB1, 0xF, 0xF, true);
    return __int_as_float(r);
}

// Two lanes per batch element (lane j owns hidden unit j). x loads are
// software-pipelined 2 float4-iterations (8 steps) ahead so the ~900-cycle
// HBM latency overlaps the serial gate math (we run at 1 wave/SIMD, so
// there is no other wave to hide it).
__global__ __launch_bounds__(64) void lstm_fused3(
    const float* __restrict__ x,      // [B, T]
    const float* __restrict__ W_ih,   // [8]
    const float* __restrict__ W_hh,   // [8, 2]
    const float* __restrict__ b_ih,   // [8]
    const float* __restrict__ b_hh,   // [8]
    const float* __restrict__ fc1_w,  // [128, 2]
    const float* __restrict__ fc1_b,  // [128]
    const float* __restrict__ fc_w,   // [128]
    const float* __restrict__ fc_b,   // [1]
    float* __restrict__ out,          // [B]
    int B)
{
    const int lane = threadIdx.x;
    const int j    = lane & 1;
    const int e    = blockIdx.x * 32 + (lane >> 1);
    if (e >= B) return;

    const float SIG = -1.4426950408889634f;   // -log2(e)
    const float TNH = -2.8853900817779268f;   // -2*log2(e)

    // Gate rows (PyTorch order): i=0+j, f=2+j, g=4+j, o=6+j (scale pre-folded).
    float a_[4], b_[4], us_[4], uo_[4];
#pragma unroll
    for (int t = 0; t < 4; ++t) {
        int r   = 2 * t + j;
        float s = (t == 2) ? TNH : SIG;
        a_[t]  = W_ih[r] * s;
        b_[t]  = (b_ih[r] + b_hh[r]) * s;
        us_[t] = W_hh[2 * r + j] * s;
        uo_[t] = W_hh[2 * r + (j ^ 1)] * s;
    }

    float h = 0.f, c = 0.f;
    const float4* xv = reinterpret_cast<const float4*>(x + (size_t)e * T_STEPS);

    float4 xA = xv[0];
    float4 xB = xv[1];

#pragma unroll 1
    for (int t4 = 0; t4 < T_STEPS / 4; t4 += 2) {
        // Prefetch 2 iterations (8 steps) ahead; wraps harmlessly at the end.
        float4 xC = xv[(t4 + 2) & (T_STEPS / 4 - 1)];
        float4 xD = xv[(t4 + 3) & (T_STEPS / 4 - 1)];

        float xs8[8] = {xA.x, xA.y, xA.z, xA.w, xB.x, xB.y, xB.z, xB.w};
#pragma unroll
        for (int k = 0; k < 8; ++k) {
            float xs = xs8[k];
            float ho = swap_pair(h);
            float zi = fmaf(ho, uo_[0], fmaf(h, us_[0], fmaf(xs, a_[0], b_[0])));
            float zf = fmaf(ho, uo_[1], fmaf(h, us_[1], fmaf(xs, a_[1], b_[1])));
            float zg = fmaf(ho, uo_[2], fmaf(h, us_[2], fmaf(xs, a_[2], b_[2])));
            float zo = fmaf(ho, uo_[3], fmaf(h, us_[3], fmaf(xs, a_[3], b_[3])));
            float ii = rcp_fast(1.f + exp2_fast(zi));
            float ff = rcp_fast(1.f + exp2_fast(zf));
            float tg = rcp_fast(1.f + exp2_fast(zg));
            float oo = rcp_fast(1.f + exp2_fast(zo));
            float gg = fmaf(2.f, tg, -1.f);
            c = fmaf(ff, c, ii * gg);
            float tc = rcp_fast(1.f + exp2_fast(c * TNH));
            h = oo * fmaf(2.f, tc, -1.f);
        }
        xA = xC;
        xB = xD;
    }

    // Head: relu -> fc1 (2->128) -> relu -> fc (128->1), split across the pair.
    float hr  = fmaxf(h, 0.f);
    float hro = swap_pair(hr);
    float h0 = j ? hro : hr;
    float h1 = j ? hr : hro;

    float part = 0.f;
    const float2* w2 = reinterpret_cast<const float2*>(fc1_w);
    int base = j * 64;
#pragma unroll 4
    for (int m = 0; m < 64; ++m) {
        int jj = base + m;
        float2 w = w2[jj];
        float v = fmaf(h1, w.y, fmaf(h0, w.x, fc1_b[jj]));
        part = fmaf(fmaxf(v, 0.f), fc_w[jj], part);
    }
    part += swap_pair(part);
    if (j == 0) out[e] = part + fc_b[0];
}

extern "C" void kernel_launch(void* const* d_in, const int* in_sizes, int n_in,
                              void* d_out, int out_size, void* d_ws, size_t ws_size,
                              hipStream_t stream) {
    const float* x     = (const float*)d_in[0];
    const float* W_ih  = (const float*)d_in[1];
    const float* W_hh  = (const float*)d_in[2];
    const float* b_ih  = (const float*)d_in[3];
    const float* b_hh  = (const float*)d_in[4];
    const float* fc1_w = (const float*)d_in[5];
    const float* fc1_b = (const float*)d_in[6];
    const float* fc_w  = (const float*)d_in[7];
    const float* fc_b  = (const float*)d_in[8];

    int B = in_sizes[0] / T_STEPS;        // 32768
    int grid = (B + 31) / 32;             // 1024 waves = 1 per SIMD
    lstm_fused3<<<grid, 64, 0, stream>>>(x, W_ih, W_hh, b_ih, b_hh,
                                         fc1_w, fc1_b, fc_w, fc_b,
                                         (float*)d_out, B);
}